// Round 16
// baseline (128.921 us; speedup 1.0000x reference)
//
#include <hip/hip_runtime.h>

typedef unsigned int uint32;

#define NN 10000
#define EE_ 80000
#define NODE_ROWS 20000
#define NODE_BLOCKS 79         // ceil(20000/256)
#define EDGE_BLOCKS 625        // 160000/256 exact
#define COLLAPSE_BLOCKS 32
#define TOTAL_BLOCKS (COLLAPSE_BLOCKS + NODE_BLOCKS + EDGE_BLOCKS)  // 736

#define FLAG_MAGIC 0x5EEDF00Du
#define CHUNKFLAG_U32 640      // 32 flags x stride 8
#define COLFLAG_U32   960      // 32 flags x stride 8
#define CHAINFLAG_U32 1280     // 2 flags x stride 8
#define PT_F 2048              // chunk slots: 32 x 4160 floats

typedef float f4 __attribute__((ext_vector_type(4)));

#define GLD4(g, l) __builtin_amdgcn_global_load_lds(                      \
    (const __attribute__((address_space(1))) void*)(g),                   \
    (__attribute__((address_space(3))) void*)(l), 16, 0, 0)
#define GLD1(g, l) __builtin_amdgcn_global_load_lds(                      \
    (const __attribute__((address_space(1))) void*)(g),                   \
    (__attribute__((address_space(3))) void*)(l), 4, 0, 0)

template<int NF>
static __device__ __forceinline__ void mlp_apply_store(const float* x, const float* sW,
                                                       float* po)
{
  float a[16];
  #pragma unroll
  for (int q = 0; q < 16; ++q) a[q] = sW[NF*16 + q];   // bias row
  #pragma unroll
  for (int j = 0; j < NF; ++j) {
    const float xv = x[j];
    #pragma unroll
    for (int q = 0; q < 16; ++q) a[q] += xv * sW[j*16 + q];
  }
  float4* d = (float4*)po;
  d[0] = make_float4(a[0],  a[1],  a[2],  a[3]);
  d[1] = make_float4(a[4],  a[5],  a[6],  a[7]);
  d[2] = make_float4(a[8],  a[9],  a[10], a[11]);
  d[3] = make_float4(a[12], a[13], a[14], a[15]);
}

// ---------------------------------------------------------------------------
// mega_kernel: 736 blocks x 256 thr, ONE dispatch.
//  blocks [0,32): chunk product -> hop -> fold16 -> weff + col flag;
//                 block q=0 aggregates 16 col flags -> chain flag
//  blocks [32,736): apply — preload x rows (pinned), poll chain flag with
//                 s_sleep(32) (1 poller/block), stage weff, FMA, store.
// MAGIC flags: poison 0xAA != MAGIC; stale MAGIC on replays is benign
// (identical inputs -> identical slot/weff bytes every call).
// ---------------------------------------------------------------------------
__global__ __launch_bounds__(256, 1) void mega_kernel(
    const float* __restrict__ nodes, const float* __restrict__ globals_,
    const float* __restrict__ edges, const int* __restrict__ senders,
    const int* __restrict__ receivers,
    const float* __restrict__ nWin, const float* __restrict__ nbin,
    const float* __restrict__ nWhid, const float* __restrict__ nbhid,
    const float* __restrict__ nWout, const float* __restrict__ nbout,
    const float* __restrict__ eWin, const float* __restrict__ ebin,
    const float* __restrict__ eWhid, const float* __restrict__ ebhid,
    const float* __restrict__ eWout, const float* __restrict__ ebout,
    float* __restrict__ ws, float* __restrict__ out)
{
  __shared__ float smem[13312];          // 53.2 KB (collapse); apply uses [0,512)
  const int t = threadIdx.x;
  uint32* ws_u = (uint32*)ws;
  float* pt = ws + PT_F;                 // 32 slots x 4160 f

  if (blockIdx.x >= COLLAPSE_BLOCKS) {
    // =================== apply block ===================
    const int ab = blockIdx.x - COLLAPSE_BLOCKS;
    const bool is_node = (ab < NODE_BLOCKS);
    // ---- preload x (independent of weff) ----
    float x[31];
    int rn = 0, re = 0, b = 0;
    bool active = true;
    if (is_node) {
      rn = ab*256 + t;
      active = (rn < NODE_ROWS);
      if (active) {
        const float* p = nodes + (size_t)rn*30;
        #pragma unroll
        for (int j = 0; j < 15; ++j) {
          float2 u = *(const float2*)(p + j*2);
          x[2*j]     = u.x;
          x[2*j + 1] = u.y;
        }
        b = (rn >= NN) ? 1 : 0;
        x[30] = globals_[b];
      }
    } else {
      re = (ab - NODE_BLOCKS)*256 + t;   // < 160000 exact
      b = (re >= EE_) ? 1 : 0;
      const float* ep = edges + (size_t)re*3;
      x[0] = ep[0]; x[1] = ep[1]; x[2] = ep[2];
      const int si = senders[re], ri = receivers[re];
      const float* ps = nodes + ((size_t)(b*NN + si))*30;
      const float* pr = nodes + ((size_t)(b*NN + ri))*30;
      const float dx = ps[0] - pr[0];
      const float dy = ps[1] - pr[1];
      const float dz = ps[2] - pr[2];
      x[3] = dx; x[4] = dy; x[5] = dz;
      x[6] = sqrtf(dx*dx + dy*dy + dz*dz);
    }
    // pin loads: forces materialization BEFORE the poll loop (no IR sink)
    if (active) {
      const int nf = is_node ? 31 : 7;
      #pragma unroll
      for (int i = 0; i < 31; ++i)
        if (i < nf) asm volatile("" :: "v"(x[i]));
    }
    // ---- poll chain flag (1 poller, long sleep) ----
    if (t == 0) {
      const uint32* p = ws_u + CHAINFLAG_U32 + (is_node ? 0 : 8);
      int guard = 0;
      while (__hip_atomic_load(p, __ATOMIC_ACQUIRE, __HIP_MEMORY_SCOPE_AGENT)
             != FLAG_MAGIC) {
        __builtin_amdgcn_s_sleep(32);
        if (++guard > (1 << 16)) break;  // bounded: fail visibly, never hang
      }
    }
    __syncthreads();
    // ---- stage weff, apply, store ----
    {
      const float* src = ws + (is_node ? 0 : 512);
      const int n = is_node ? 512 : 128;
      for (int j = t; j < n; j += 256) smem[j] = src[j];
    }
    __syncthreads();
    if (!active) return;
    if (is_node) mlp_apply_store<31>(x, smem, out + (size_t)rn*16);
    else         mlp_apply_store<7>(x, smem, out + (size_t)(NODE_ROWS + re)*16);
    return;
  }

  // =================== collapse block (R15 body, proven) ===================
  const int c  = blockIdx.x >> 4;        // 0 node, 1 edge
  const int jq = blockIdx.x & 15;        // phase1: chunk j; phase2: column q

  // ---------------- phase 1: chunk product ----------------
  {
    float* s_at = smem;                  // [2][4352]: A^T [k][r], col64 = A.b
    float* s_b  = smem + 8704;           // B rows + bias row (4160)
    float* s_bp = smem + 12864;          // 256
    const float* Wh = c ? eWhid : nWhid;
    const float* bh = c ? ebhid : nbhid;
    const int L0 = 4*jq;

    for (int idx = t; idx < 4160; idx += 256) {
      int r = idx >> 6, k = idx & 63;
      s_at[k*68 + r] = (r < 64) ? Wh[(size_t)L0*4096 + idx] : bh[L0*64 + k];
    }
    int cur = 0;
    #pragma unroll 1
    for (int s = 1; s <= 3; ++s) {
      const float* WB = Wh + (size_t)(L0 + s)*4096;
      const float* bB = bh + (size_t)(L0 + s)*64;
      #pragma unroll
      for (int i = 0; i < 4; ++i) {
        int i4 = t + i*256;
        *(float4*)&s_b[i4*4] = *(const float4*)&WB[i4*4];
      }
      if (t < 16) *(float4*)&s_b[4096 + t*4] = *(const float4*)&bB[t*4];
      __syncthreads();

      const int ti = t >> 4, tj = t & 15;
      float acc[4][4];
      #pragma unroll
      for (int d = 0; d < 4; ++d)
        #pragma unroll
        for (int e = 0; e < 4; ++e) acc[d][e] = 0.f;
      #pragma unroll 4
      for (int k = 0; k < 64; ++k) {
        float4 a4 = *(const float4*)&s_at[cur*4352 + k*68 + 4*ti];
        float4 b4 = *(const float4*)&s_b[k*64 + 4*tj];
        float av[4] = {a4.x, a4.y, a4.z, a4.w};
        float bv[4] = {b4.x, b4.y, b4.z, b4.w};
        #pragma unroll
        for (int d = 0; d < 4; ++d)
          #pragma unroll
          for (int e = 0; e < 4; ++e) acc[d][e] += av[d]*bv[e];
      }
      {
        int cc2 = t & 63, kq = t >> 6;
        float p = 0.f;
        #pragma unroll 4
        for (int kk = 0; kk < 16; ++kk) {
          int k = kq*16 + kk;
          p += s_at[cur*4352 + k*68 + 64] * s_b[k*64 + cc2];
        }
        s_bp[kq*64 + cc2] = p;
      }
      __syncthreads();
      if (s < 3) {
        #pragma unroll
        for (int d = 0; d < 4; ++d)
          #pragma unroll
          for (int e = 0; e < 4; ++e)
            s_at[(cur^1)*4352 + (4*tj + e)*68 + 4*ti + d] = acc[d][e];
        if (t < 64)
          s_at[(cur^1)*4352 + t*68 + 64] =
              s_bp[t] + s_bp[64+t] + s_bp[128+t] + s_bp[192+t] + s_b[4096+t];
        __syncthreads();
        cur ^= 1;
      } else {
        float* D = pt + (size_t)(c*16 + jq)*4160;
        #pragma unroll
        for (int d = 0; d < 4; ++d)
          *(float4*)&D[(4*ti + d)*64 + 4*tj] =
              make_float4(acc[d][0], acc[d][1], acc[d][2], acc[d][3]);
        if (t < 64)
          D[4096 + t] = s_bp[t] + s_bp[64+t] + s_bp[128+t] + s_bp[192+t] + s_b[4096+t];
      }
    }
  }

  // ---- release own chunk flag; acquire all 16 chain chunk flags ----
  __syncthreads();
  if (t == 0) {
    __threadfence();
    __hip_atomic_store(ws_u + CHUNKFLAG_U32 + (c*16 + jq)*8, FLAG_MAGIC,
                       __ATOMIC_RELEASE, __HIP_MEMORY_SCOPE_AGENT);
  }
  if (t < 16) {
    const uint32* p = ws_u + CHUNKFLAG_U32 + (c*16 + t)*8;
    int guard = 0;
    while (__hip_atomic_load(p, __ATOMIC_ACQUIRE, __HIP_MEMORY_SCOPE_AGENT)
           != FLAG_MAGIC) {
      __builtin_amdgcn_s_sleep(2);
      if (++guard > (1 << 20)) break;
    }
  }
  __syncthreads();

  // ---------------- phase 2: fold16 column q ----------------
  {
    float* lds_f = smem;
    const int lane = t & 63;
    const int wv   = __builtin_amdgcn_readfirstlane(t >> 6);  // 0..3
    const int q = jq;
    const float* Win  = c ? eWin  : nWin;
    const float* bin  = c ? ebin  : nbin;
    const float* Wout = c ? eWout : nWout;
    const float* bout = c ? ebout : nbout;
    const float* PT = pt + (size_t)c*16*4160;
    const int din = c ? 7 : 31;
    float* weff = ws + (c ? 512 : 0);

    const int r4 = lane >> 4, c16 = lane & 15;
    const int oE = r4*64 + ((c16 ^ r4) << 2);        // GLD4 slot parity even
    const int oO = r4*64 + ((c16 ^ (4 | r4)) << 2);  // GLD4 slot parity odd
    const int swz = lane & 7;
    const int aw0 = lane*256 + (((4*wv + 0) ^ swz) << 4);
    const int aw1 = lane*256 + (((4*wv + 1) ^ swz) << 4);
    const int aw2 = lane*256 + (((4*wv + 2) ^ swz) << 4);
    const int aw3 = lane*256 + (((4*wv + 3) ^ swz) << 4);
    const int ab2 = 16384 + wv*256 + lane*4;
    const int apw = 52224 + lane*16 + wv*4;
    const int apr = 52224 + lane*16;

    float vlane = Wout[lane*16 + q];
    float bpart = 0.f;
    const int kbase = 16*wv;
    float s[16];
    #pragma unroll
    for (int j = 0; j < 16; ++j)
      s[j] = __uint_as_float(__builtin_amdgcn_readlane(__float_as_uint(vlane), kbase + j));

#define STAGE(BF, L) do {                                                 \
    const float* gW_ = PT + (size_t)(L)*4160 + wv*1024;                   \
    float* lW_ = lds_f + (BF)*4352 + wv*1024;                             \
    GLD4(gW_ +   0 + oE, lW_ +   0);                                      \
    GLD4(gW_ + 256 + oO, lW_ + 256);                                      \
    GLD4(gW_ + 512 + oE, lW_ + 512);                                      \
    GLD4(gW_ + 768 + oO, lW_ + 768);                                      \
    GLD1(PT + (size_t)(L)*4160 + 4096 + lane,                             \
         lds_f + (BF)*4352 + 4096 + wv*64);                               \
  } while (0)

#define CSTEP(OFS, VMC, STAGESTMT) do {                                   \
    STAGESTMT;                                                            \
    asm volatile("s_waitcnt vmcnt(" #VMC ") lgkmcnt(0)" ::: "memory");    \
    __builtin_amdgcn_s_barrier();                                         \
    f4 f0_, f1_, f2_, f3_; float bb_;                                     \
    asm volatile("ds_read_b128 %0, %5 offset:" #OFS "\n\t"                \
                 "ds_read_b128 %1, %6 offset:" #OFS "\n\t"                \
                 "ds_read_b128 %2, %7 offset:" #OFS "\n\t"                \
                 "ds_read_b128 %3, %8 offset:" #OFS "\n\t"                \
                 "ds_read_b32  %4, %9 offset:" #OFS "\n\t"                \
                 "s_waitcnt lgkmcnt(0)"                                   \
                 : "=&v"(f0_), "=&v"(f1_), "=&v"(f2_), "=&v"(f3_), "=&v"(bb_) \
                 : "v"(aw0), "v"(aw1), "v"(aw2), "v"(aw3), "v"(ab2)       \
                 : "memory");                                             \
    __builtin_amdgcn_sched_barrier(0);                                    \
    bpart = __builtin_fmaf(bb_, vlane, bpart);                            \
    float a0_ = __builtin_fmaf(f0_.y, s[1],  f0_.x * s[0]);               \
    a0_ = __builtin_fmaf(f0_.z, s[2],  a0_);                              \
    a0_ = __builtin_fmaf(f0_.w, s[3],  a0_);                              \
    float a1_ = __builtin_fmaf(f1_.y, s[5],  f1_.x * s[4]);               \
    a1_ = __builtin_fmaf(f1_.z, s[6],  a1_);                              \
    a1_ = __builtin_fmaf(f1_.w, s[7],  a1_);                              \
    float a2_ = __builtin_fmaf(f2_.y, s[9],  f2_.x * s[8]);               \
    a2_ = __builtin_fmaf(f2_.z, s[10], a2_);                              \
    a2_ = __builtin_fmaf(f2_.w, s[11], a2_);                              \
    float a3_ = __builtin_fmaf(f3_.y, s[13], f3_.x * s[12]);              \
    a3_ = __builtin_fmaf(f3_.z, s[14], a3_);                              \
    a3_ = __builtin_fmaf(f3_.w, s[15], a3_);                              \
    float acc_ = (a0_ + a1_) + (a2_ + a3_);                               \
    asm volatile("ds_write_b32 %0, %1\n\t"                                \
                 "s_waitcnt lgkmcnt(0)"                                   \
                 :: "v"(apw), "v"(acc_) : "memory");                      \
    __builtin_amdgcn_s_barrier();                                         \
    f4 p4_;                                                               \
    asm volatile("ds_read_b128 %0, %1\n\t"                                \
                 "s_waitcnt lgkmcnt(0)"                                   \
                 : "=&v"(p4_) : "v"(apr) : "memory");                     \
    __builtin_amdgcn_sched_barrier(0);                                    \
    vlane = (p4_.x + p4_.y) + (p4_.z + p4_.w);                            \
    _Pragma("unroll")                                                     \
    for (int jj = 0; jj < 16; ++jj)                                       \
      s[jj] = __uint_as_float(__builtin_amdgcn_readlane(                  \
                  __float_as_uint(vlane), kbase + jj));                   \
  } while (0)

    STAGE(0, 15);
    STAGE(1, 14);

    int L = 15;
    #pragma unroll 1
    for (int ii = 0; ii < 4; ++ii) {     // chunks 15..4
      CSTEP(0,     10, STAGE(2, L-2));
      CSTEP(17408, 10, STAGE(0, L-3));
      CSTEP(34816, 10, STAGE(1, L-4));
      L -= 3;
    }
    CSTEP(0,     10, STAGE(2, 1));
    CSTEP(17408, 10, STAGE(0, 0));
    CSTEP(34816, 5,  (void)0);
    CSTEP(0,     0,  (void)0);
#undef CSTEP
#undef STAGE

    if (wv != 0) return;

    float red = __builtin_fmaf(bin[lane], vlane, bpart);
    #pragma unroll
    for (int off = 32; off > 0; off >>= 1) red += __shfl_xor(red, off, 64);

    float* sv = lds_f;
    sv[lane] = vlane;
    __builtin_amdgcn_sched_barrier(0);

    if (lane == din) {
      weff[din*16 + q] = red + bout[q];
    } else if (lane < din) {
      float a0 = 0.f, a1 = 0.f, a2 = 0.f, a3 = 0.f;
      const float* wr = Win + (size_t)lane*64;
      #pragma unroll
      for (int kb = 0; kb < 16; ++kb) {
        f4 vv = *(const f4*)&sv[kb*4];
        f4 wv4 = *(const f4*)&wr[kb*4];
        a0 = __builtin_fmaf(wv4.x, vv.x, a0);
        a1 = __builtin_fmaf(wv4.y, vv.y, a1);
        a2 = __builtin_fmaf(wv4.z, vv.z, a2);
        a3 = __builtin_fmaf(wv4.w, vv.w, a3);
      }
      weff[lane*16 + q] = (a0 + a1) + (a2 + a3);
    }

    // ---- column flag; block q==0 aggregates -> chain flag ----
    __threadfence();                     // weff stores visible device-wide
    if (lane == 0)
      __hip_atomic_store(ws_u + COLFLAG_U32 + (c*16 + q)*8, FLAG_MAGIC,
                         __ATOMIC_RELEASE, __HIP_MEMORY_SCOPE_AGENT);
    if (q == 0) {
      if (lane < 16) {
        const uint32* p = ws_u + COLFLAG_U32 + (c*16 + lane)*8;
        int guard = 0;
        while (__hip_atomic_load(p, __ATOMIC_ACQUIRE, __HIP_MEMORY_SCOPE_AGENT)
               != FLAG_MAGIC) {
          __builtin_amdgcn_s_sleep(2);
          if (++guard > (1 << 20)) break;
        }
      }
      // wave reconverges; release chain flag
      if (lane == 0)
        __hip_atomic_store(ws_u + CHAINFLAG_U32 + c*8, FLAG_MAGIC,
                           __ATOMIC_RELEASE, __HIP_MEMORY_SCOPE_AGENT);
    }
  }
}

extern "C" void kernel_launch(void* const* d_in, const int* in_sizes, int n_in,
                              void* d_out, int out_size, void* d_ws, size_t ws_size,
                              hipStream_t stream)
{
  const float* nodes    = (const float*)d_in[0];
  const float* globals_ = (const float*)d_in[1];
  const float* edges    = (const float*)d_in[2];
  const int* senders   = (const int*)d_in[3];
  const int* receivers = (const int*)d_in[4];
  const float* nWin  = (const float*)d_in[5];
  const float* nbin  = (const float*)d_in[6];
  const float* nWhid = (const float*)d_in[7];
  const float* nbhid = (const float*)d_in[8];
  const float* nWout = (const float*)d_in[9];
  const float* nbout = (const float*)d_in[10];
  const float* eWin  = (const float*)d_in[11];
  const float* ebin  = (const float*)d_in[12];
  const float* eWhid = (const float*)d_in[13];
  const float* ebhid = (const float*)d_in[14];
  const float* eWout = (const float*)d_in[15];
  const float* ebout = (const float*)d_in[16];
  float* ws  = (float*)d_ws;
  float* out = (float*)d_out;

  mega_kernel<<<TOTAL_BLOCKS, 256, 0, stream>>>(
      nodes, globals_, edges, senders, receivers,
      nWin, nbin, nWhid, nbhid, nWout, nbout,
      eWin, ebin, eWhid, ebhid, eWout, ebout, ws, out);
}

// Round 17
// 42.006 us; speedup vs baseline: 3.0691x; 3.0691x over previous
//
#include <hip/hip_runtime.h>

#define NN 10000
#define EE_ 80000
#define NODE_ROWS 20000
#define NODE_BLOCKS 79         // ceil(20000/256)
#define EDGE_BLOCKS 625        // 160000/256 exact

typedef float f4 __attribute__((ext_vector_type(4)));

#define GLD4(g, l) __builtin_amdgcn_global_load_lds(                      \
    (const __attribute__((address_space(1))) void*)(g),                   \
    (__attribute__((address_space(3))) void*)(l), 16, 0, 0)
#define GLD1(g, l) __builtin_amdgcn_global_load_lds(                      \
    (const __attribute__((address_space(1))) void*)(g),                   \
    (__attribute__((address_space(3))) void*)(l), 4, 0, 0)

// ---------------------------------------------------------------------------
// D1: chunk_half_kernel — 64 blocks x 128 thr. Block (c,j,h): rows
// [32h,32h+32) of the augmented product of layers 4j..4j+3, exploiting
// (A@B@C@D)[rows] = A[rows]@B@C@D (B,C,D are inputs -> row-split is free).
// Halves per-GEMM LDS instruction count vs R13's 32-block version.
// Bias row (1x64) computed in h==0 only. Output slot layout = R13.
// ---------------------------------------------------------------------------
__global__ __launch_bounds__(128) void chunk_half_kernel(
    const float* __restrict__ nWhid, const float* __restrict__ nbhid,
    const float* __restrict__ eWhid, const float* __restrict__ ebhid,
    float* __restrict__ pt)
{
  const int t = threadIdx.x;
  const int c = blockIdx.x >> 5;
  const int j = (blockIdx.x >> 1) & 15;
  const int h = blockIdx.x & 1;
  const float* Wh = c ? eWhid : nWhid;
  const float* bh = c ? ebhid : nbhid;
  const int L0 = 4*j;

  __shared__ float s_at[2][64*36];   // A^T-half: [k][r], r<32; col 32 = A.b[k] (h==0)
  __shared__ float s_b[65*64];       // B rows + bias row
  __shared__ float s_bp[128];        // 2-wave bias partials

  // stage A-half = rows [32h,32h+32) of W_{L0}, transposed (+ bias col, h==0)
  #pragma unroll
  for (int i = 0; i < 16; ++i) {
    int idx = t + i*128;             // 2048 elems
    int r = idx >> 6, k = idx & 63;
    s_at[0][k*36 + r] = Wh[(size_t)L0*4096 + (32*h + r)*64 + k];
  }
  if (h == 0 && t < 64) s_at[0][t*36 + 32] = bh[L0*64 + t];

  int cur = 0;
  #pragma unroll 1
  for (int s = 1; s <= 3; ++s) {
    const float* WB = Wh + (size_t)(L0 + s)*4096;
    const float* bB = bh + (size_t)(L0 + s)*64;
    #pragma unroll
    for (int i = 0; i < 9; ++i) {
      int i4 = t + i*128;
      if (i4 < 1024) *(float4*)&s_b[i4*4] = *(const float4*)&WB[i4*4];
    }
    if (t < 16) *(float4*)&s_b[4096 + t*4] = *(const float4*)&bB[t*4];
    __syncthreads();

    const int ti = t >> 4, tj = t & 15;     // rows 4ti..4ti+3 (of 32), cols 4tj..
    float acc[4][4];
    #pragma unroll
    for (int d = 0; d < 4; ++d)
      #pragma unroll
      for (int e = 0; e < 4; ++e) acc[d][e] = 0.f;
    #pragma unroll 4
    for (int k = 0; k < 64; ++k) {
      float4 a4 = *(const float4*)&s_at[cur][k*36 + 4*ti];
      float4 b4 = *(const float4*)&s_b[k*64 + 4*tj];
      float av[4] = {a4.x, a4.y, a4.z, a4.w};
      float bv[4] = {b4.x, b4.y, b4.z, b4.w};
      #pragma unroll
      for (int d = 0; d < 4; ++d)
        #pragma unroll
        for (int e = 0; e < 4; ++e) acc[d][e] += av[d]*bv[e];
    }
    // bias partials (h==0): b' = A.b @ B.W + B.b, k-split over 2 waves
    if (h == 0) {
      int cc = t & 63, kq = t >> 6;
      float p = 0.f;
      #pragma unroll 4
      for (int kk = 0; kk < 32; ++kk) {
        int k = kq*32 + kk;
        p += s_at[cur][k*36 + 32] * s_b[k*64 + cc];
      }
      s_bp[kq*64 + cc] = p;
    }
    __syncthreads();
    if (s < 3) {
      // write M^T into the other A buffer (M = 32x64 partial product)
      #pragma unroll
      for (int d = 0; d < 4; ++d)
        #pragma unroll
        for (int e = 0; e < 4; ++e)
          s_at[cur^1][(4*tj + e)*36 + 4*ti + d] = acc[d][e];
      if (h == 0 && t < 64)
        s_at[cur^1][t*36 + 32] = s_bp[t] + s_bp[64 + t] + s_b[4096 + t];
      __syncthreads();
      cur ^= 1;
    } else {
      float* D = pt + (size_t)(c*16 + j)*4160;
      #pragma unroll
      for (int d = 0; d < 4; ++d)
        *(float4*)&D[(32*h + 4*ti + d)*64 + 4*tj] =
            make_float4(acc[d][0], acc[d][1], acc[d][2], acc[d][3]);
      if (h == 0 && t < 64)
        D[4096 + t] = s_bp[t] + s_bp[64 + t] + s_b[4096 + t];
    }
  }
}

// ---------------------------------------------------------------------------
// D2: fold16_kernel (verbatim R13, passed). 32 blocks x 256 thr (4 waves).
// Block (c,q): column q of chain c; wave w owns k-slice [16w,16w+16);
// v via readlane SGPRs; chunks staged 2-deep into 3 LDS buffers via
// global_load_lds, counted vmcnt(10).
// ws: [0..512) node W_eff 32x16, [512..640) edge 8x16.
// ---------------------------------------------------------------------------
__global__ __launch_bounds__(256, 1) void fold16_kernel(
    const float* __restrict__ nWin, const float* __restrict__ nbin,
    const float* __restrict__ nWout, const float* __restrict__ nbout,
    const float* __restrict__ eWin, const float* __restrict__ ebin,
    const float* __restrict__ eWout, const float* __restrict__ ebout,
    const float* __restrict__ pt, float* __restrict__ ws)
{
  const int tid  = threadIdx.x;
  const int lane = tid & 63;
  const int wv   = __builtin_amdgcn_readfirstlane(tid >> 6);  // 0..3
  const int c = blockIdx.x >> 4;         // 0 node, 1 edge
  const int q = blockIdx.x & 15;         // output column
  const float* Win  = c ? eWin  : nWin;
  const float* bin  = c ? ebin  : nbin;
  const float* Wout = c ? eWout : nWout;
  const float* bout = c ? ebout : nbout;
  const float* PT = pt + (size_t)c*16*4160;
  const int din = c ? 7 : 31;
  float* weff = ws + (c ? 512 : 0);

  __shared__ float lds_f[13312];   // 3*4352 buffers + 256 partials = 53 KB

  const int r4 = lane >> 4, c16 = lane & 15;
  const int oE = r4*64 + ((c16 ^ r4) << 2);        // GLD4 slot parity even
  const int oO = r4*64 + ((c16 ^ (4 | r4)) << 2);  // GLD4 slot parity odd
  const int swz = lane & 7;
  const int aw0 = lane*256 + (((4*wv + 0) ^ swz) << 4);
  const int aw1 = lane*256 + (((4*wv + 1) ^ swz) << 4);
  const int aw2 = lane*256 + (((4*wv + 2) ^ swz) << 4);
  const int aw3 = lane*256 + (((4*wv + 3) ^ swz) << 4);
  const int ab  = 16384 + wv*256 + lane*4;          // bias copy (per-wave)
  const int apw = 52224 + lane*16 + wv*4;           // partial write
  const int apr = 52224 + lane*16;                  // partial read (b128)

  float vlane = Wout[lane*16 + q];                  // V_16 column = Wout[:,q]
  float bpart = 0.f;
  const int kbase = 16*wv;
  float s[16];
  #pragma unroll
  for (int j = 0; j < 16; ++j)
    s[j] = __uint_as_float(__builtin_amdgcn_readlane(__float_as_uint(vlane), kbase + j));

#define STAGE(BF, L) do {                                                 \
    const float* gW_ = PT + (size_t)(L)*4160 + wv*1024;                   \
    float* lW_ = lds_f + (BF)*4352 + wv*1024;                             \
    GLD4(gW_ +   0 + oE, lW_ +   0);                                      \
    GLD4(gW_ + 256 + oO, lW_ + 256);                                      \
    GLD4(gW_ + 512 + oE, lW_ + 512);                                      \
    GLD4(gW_ + 768 + oO, lW_ + 768);                                      \
    GLD1(PT + (size_t)(L)*4160 + 4096 + lane,                             \
         lds_f + (BF)*4352 + 4096 + wv*64);                               \
  } while (0)

#define CSTEP(OFS, VMC, STAGESTMT) do {                                   \
    STAGESTMT;                                                            \
    asm volatile("s_waitcnt vmcnt(" #VMC ") lgkmcnt(0)" ::: "memory");    \
    __builtin_amdgcn_s_barrier();        /* this step's buffer ready */   \
    f4 f0_, f1_, f2_, f3_; float bb_;                                     \
    asm volatile("ds_read_b128 %0, %5 offset:" #OFS "\n\t"                \
                 "ds_read_b128 %1, %6 offset:" #OFS "\n\t"                \
                 "ds_read_b128 %2, %7 offset:" #OFS "\n\t"                \
                 "ds_read_b128 %3, %8 offset:" #OFS "\n\t"                \
                 "ds_read_b32  %4, %9 offset:" #OFS "\n\t"                \
                 "s_waitcnt lgkmcnt(0)"                                   \
                 : "=&v"(f0_), "=&v"(f1_), "=&v"(f2_), "=&v"(f3_), "=&v"(bb_) \
                 : "v"(aw0), "v"(aw1), "v"(aw2), "v"(aw3), "v"(ab)        \
                 : "memory");                                             \
    __builtin_amdgcn_sched_barrier(0);                                    \
    bpart = __builtin_fmaf(bb_, vlane, bpart);                            \
    float a0_ = __builtin_fmaf(f0_.y, s[1],  f0_.x * s[0]);               \
    a0_ = __builtin_fmaf(f0_.z, s[2],  a0_);                              \
    a0_ = __builtin_fmaf(f0_.w, s[3],  a0_);                              \
    float a1_ = __builtin_fmaf(f1_.y, s[5],  f1_.x * s[4]);               \
    a1_ = __builtin_fmaf(f1_.z, s[6],  a1_);                              \
    a1_ = __builtin_fmaf(f1_.w, s[7],  a1_);                              \
    float a2_ = __builtin_fmaf(f2_.y, s[9],  f2_.x * s[8]);               \
    a2_ = __builtin_fmaf(f2_.z, s[10], a2_);                              \
    a2_ = __builtin_fmaf(f2_.w, s[11], a2_);                              \
    float a3_ = __builtin_fmaf(f3_.y, s[13], f3_.x * s[12]);              \
    a3_ = __builtin_fmaf(f3_.z, s[14], a3_);                              \
    a3_ = __builtin_fmaf(f3_.w, s[15], a3_);                              \
    float acc_ = (a0_ + a1_) + (a2_ + a3_);                               \
    asm volatile("ds_write_b32 %0, %1\n\t"                                \
                 "s_waitcnt lgkmcnt(0)"                                   \
                 :: "v"(apw), "v"(acc_) : "memory");                      \
    __builtin_amdgcn_s_barrier();        /* partials visible */           \
    f4 p4_;                                                               \
    asm volatile("ds_read_b128 %0, %1\n\t"                                \
                 "s_waitcnt lgkmcnt(0)"                                   \
                 : "=&v"(p4_) : "v"(apr) : "memory");                     \
    __builtin_amdgcn_sched_barrier(0);                                    \
    vlane = (p4_.x + p4_.y) + (p4_.z + p4_.w);                            \
    _Pragma("unroll")                                                     \
    for (int jj = 0; jj < 16; ++jj)                                       \
      s[jj] = __uint_as_float(__builtin_amdgcn_readlane(                  \
                  __float_as_uint(vlane), kbase + jj));                   \
  } while (0)

  // prologue: prime buffers 0 (chunk 15) and 1 (chunk 14) -> 10 outstanding
  STAGE(0, 15);
  STAGE(1, 14);

  int L = 15;
  #pragma unroll 1
  for (int ii = 0; ii < 4; ++ii) {       // chunks 15..4
    CSTEP(0,     10, STAGE(2, L-2));
    CSTEP(17408, 10, STAGE(0, L-3));
    CSTEP(34816, 10, STAGE(1, L-4));
    L -= 3;
  }
  // tail: chunks 3,2,1,0
  CSTEP(0,     10, STAGE(2, 1));
  CSTEP(17408, 10, STAGE(0, 0));
  CSTEP(34816, 5,  (void)0);
  CSTEP(0,     0,  (void)0);
#undef CSTEP
#undef STAGE
  // vlane == V_0[lane]; bpart = lane's share of beta (identical in all waves)

  if (wv != 0) return;                   // no barriers below

  float red = __builtin_fmaf(bin[lane], vlane, bpart);
  #pragma unroll
  for (int off = 32; off > 0; off >>= 1) red += __shfl_xor(red, off, 64);

  float* sv = lds_f;                     // buffers dead; share v0 wave-locally
  sv[lane] = vlane;
  __builtin_amdgcn_sched_barrier(0);

  if (lane == din) {
    weff[din*16 + q] = red + bout[q];
  } else if (lane < din) {
    float a0 = 0.f, a1 = 0.f, a2 = 0.f, a3 = 0.f;
    const float* wr = Win + (size_t)lane*64;
    #pragma unroll
    for (int kb = 0; kb < 16; ++kb) {
      f4 vv = *(const f4*)&sv[kb*4];
      f4 wv4 = *(const f4*)&wr[kb*4];
      a0 = __builtin_fmaf(wv4.x, vv.x, a0);
      a1 = __builtin_fmaf(wv4.y, vv.y, a1);
      a2 = __builtin_fmaf(wv4.z, vv.z, a2);
      a3 = __builtin_fmaf(wv4.w, vv.w, a3);
    }
    weff[lane*16 + q] = (a0 + a1) + (a2 + a3);
  }
}

// ---------------------------------------------------------------------------
// D3: apply (verbatim R3..R13, ~2.3 µs)
// ---------------------------------------------------------------------------
template<int NF>
static __device__ __forceinline__ void mlp_apply_store(const float* x, const float* sW,
                                                       float* po)
{
  float a[16];
  #pragma unroll
  for (int q = 0; q < 16; ++q) a[q] = sW[NF*16 + q];   // bias row
  #pragma unroll
  for (int j = 0; j < NF; ++j) {
    const float xv = x[j];
    #pragma unroll
    for (int q = 0; q < 16; ++q) a[q] += xv * sW[j*16 + q];
  }
  float4* d = (float4*)po;
  d[0] = make_float4(a[0],  a[1],  a[2],  a[3]);
  d[1] = make_float4(a[4],  a[5],  a[6],  a[7]);
  d[2] = make_float4(a[8],  a[9],  a[10], a[11]);
  d[3] = make_float4(a[12], a[13], a[14], a[15]);
}

__global__ __launch_bounds__(256) void apply_kernel(
    const float* __restrict__ nodes, const float* __restrict__ globals_,
    const float* __restrict__ edges, const int* __restrict__ senders,
    const int* __restrict__ receivers, const float* __restrict__ ws,
    float* __restrict__ out)
{
  __shared__ float sW[32*16];
  const bool is_node = (blockIdx.x < NODE_BLOCKS);
  {
    const float* src = is_node ? ws : ws + 512;
    const int n = is_node ? 32*16 : 8*16;
    for (int j = threadIdx.x; j < n; j += 256) sW[j] = src[j];
  }
  __syncthreads();

  if (is_node) {
    const int rn = blockIdx.x*256 + threadIdx.x;
    if (rn >= NODE_ROWS) return;
    float x[31];
    const float* p = nodes + (size_t)rn*30;
    #pragma unroll
    for (int j = 0; j < 15; ++j) {
      float2 u = *(const float2*)(p + j*2);
      x[2*j]     = u.x;
      x[2*j + 1] = u.y;
    }
    const int b = (rn >= NN) ? 1 : 0;
    x[30] = globals_[b];
    mlp_apply_store<31>(x, sW, out + (size_t)rn*16);
  } else {
    const int re = (blockIdx.x - NODE_BLOCKS)*256 + threadIdx.x;  // < 160000 exact
    const int b = (re >= EE_) ? 1 : 0;
    float x[7];
    const float* ep = edges + (size_t)re*3;
    x[0] = ep[0]; x[1] = ep[1]; x[2] = ep[2];
    const int si = senders[re], ri = receivers[re];
    const float* ps = nodes + ((size_t)(b*NN + si))*30;
    const float* pr = nodes + ((size_t)(b*NN + ri))*30;
    const float dx = ps[0] - pr[0];
    const float dy = ps[1] - pr[1];
    const float dz = ps[2] - pr[2];
    x[3] = dx; x[4] = dy; x[5] = dz;
    x[6] = sqrtf(dx*dx + dy*dy + dz*dz);
    mlp_apply_store<7>(x, sW, out + (size_t)(NODE_ROWS + re)*16);
  }
}

extern "C" void kernel_launch(void* const* d_in, const int* in_sizes, int n_in,
                              void* d_out, int out_size, void* d_ws, size_t ws_size,
                              hipStream_t stream)
{
  const float* nodes    = (const float*)d_in[0];
  const float* globals_ = (const float*)d_in[1];
  const float* edges    = (const float*)d_in[2];
  const int* senders   = (const int*)d_in[3];
  const int* receivers = (const int*)d_in[4];
  const float* nWin  = (const float*)d_in[5];
  const float* nbin  = (const float*)d_in[6];
  const float* nWhid = (const float*)d_in[7];
  const float* nbhid = (const float*)d_in[8];
  const float* nWout = (const float*)d_in[9];
  const float* nbout = (const float*)d_in[10];
  const float* eWin  = (const float*)d_in[11];
  const float* ebin  = (const float*)d_in[12];
  const float* eWhid = (const float*)d_in[13];
  const float* ebhid = (const float*)d_in[14];
  const float* eWout = (const float*)d_in[15];
  const float* ebout = (const float*)d_in[16];
  float* ws  = (float*)d_ws;
  float* out = (float*)d_out;
  float* pt  = ws + 1024;               // 32 slots x 4160 f

  chunk_half_kernel<<<64, 128, 0, stream>>>(nWhid, nbhid, eWhid, ebhid, pt);

  fold16_kernel<<<32, 256, 0, stream>>>(
      nWin, nbin, nWout, nbout, eWin, ebin, eWout, ebout, pt, ws);

  apply_kernel<<<NODE_BLOCKS + EDGE_BLOCKS, 256, 0, stream>>>(
      nodes, globals_, edges, senders, receivers, ws, out);
}

// Round 18
// 36.927 us; speedup vs baseline: 3.4912x; 1.1375x over previous
//
#include <hip/hip_runtime.h>

#define NN 10000
#define EE_ 80000
#define NODE_ROWS 20000
#define NODE_BLOCKS 79         // ceil(20000/256)
#define EDGE_BLOCKS 625        // 160000/256 exact

typedef float f4 __attribute__((ext_vector_type(4)));

#define GLD4(g, l) __builtin_amdgcn_global_load_lds(                      \
    (const __attribute__((address_space(1))) void*)(g),                   \
    (__attribute__((address_space(3))) void*)(l), 16, 0, 0)
#define GLD1(g, l) __builtin_amdgcn_global_load_lds(                      \
    (const __attribute__((address_space(1))) void*)(g),                   \
    (__attribute__((address_space(3))) void*)(l), 4, 0, 0)

// ---------------------------------------------------------------------------
// D1: chunk_kernel (R12/R13 verbatim, 36.9 µs pipeline) — 32 blocks x 256 thr.
// Block (c,j): augmented product of layers 4j..4j+3.
// Output slot pt[(c*16+j)*4160]: [0..4096) W row-major, [4096..4160) bias.
// NOTE (R17 lesson): do NOT row-split this into 128-thr blocks — 2-wave
// blocks lose the TLP that hides LDS/staging latency (+5 µs measured).
// ---------------------------------------------------------------------------
__global__ __launch_bounds__(256) void chunk_kernel(
    const float* __restrict__ nWhid, const float* __restrict__ nbhid,
    const float* __restrict__ eWhid, const float* __restrict__ ebhid,
    float* __restrict__ pt)
{
  const int t = threadIdx.x;
  const int c = blockIdx.x >> 4;
  const int j = blockIdx.x & 15;
  const float* Wh = c ? eWhid : nWhid;
  const float* bh = c ? ebhid : nbhid;
  const int L0 = 4*j;

  __shared__ float s_at[2][64*68];   // A^T: [k][r], col 64 = A.b[k]
  __shared__ float s_b[65*64];       // B rows + bias row
  __shared__ float s_bp[256];

  for (int idx = t; idx < 4160; idx += 256) {
    int r = idx >> 6, k = idx & 63;
    s_at[0][k*68 + r] = (r < 64) ? Wh[(size_t)L0*4096 + idx] : bh[L0*64 + k];
  }
  int cur = 0;
  #pragma unroll 1
  for (int s = 1; s <= 3; ++s) {
    const float* WB = Wh + (size_t)(L0 + s)*4096;
    const float* bB = bh + (size_t)(L0 + s)*64;
    #pragma unroll
    for (int i = 0; i < 4; ++i) {
      int i4 = t + i*256;
      *(float4*)&s_b[i4*4] = *(const float4*)&WB[i4*4];
    }
    if (t < 16) *(float4*)&s_b[4096 + t*4] = *(const float4*)&bB[t*4];
    __syncthreads();

    const int ti = t >> 4, tj = t & 15;
    float acc[4][4];
    #pragma unroll
    for (int d = 0; d < 4; ++d)
      #pragma unroll
      for (int e = 0; e < 4; ++e) acc[d][e] = 0.f;
    #pragma unroll 4
    for (int k = 0; k < 64; ++k) {
      float4 a4 = *(const float4*)&s_at[cur][k*68 + 4*ti];
      float4 b4 = *(const float4*)&s_b[k*64 + 4*tj];
      float av[4] = {a4.x, a4.y, a4.z, a4.w};
      float bv[4] = {b4.x, b4.y, b4.z, b4.w};
      #pragma unroll
      for (int d = 0; d < 4; ++d)
        #pragma unroll
        for (int e = 0; e < 4; ++e) acc[d][e] += av[d]*bv[e];
    }
    {
      int cc = t & 63, kq = t >> 6;
      float p = 0.f;
      #pragma unroll 4
      for (int kk = 0; kk < 16; ++kk) {
        int k = kq*16 + kk;
        p += s_at[cur][k*68 + 64] * s_b[k*64 + cc];
      }
      s_bp[kq*64 + cc] = p;
    }
    __syncthreads();
    if (s < 3) {
      #pragma unroll
      for (int d = 0; d < 4; ++d)
        #pragma unroll
        for (int e = 0; e < 4; ++e)
          s_at[cur^1][(4*tj + e)*68 + 4*ti + d] = acc[d][e];
      if (t < 64)
        s_at[cur^1][t*68 + 64] =
            s_bp[t] + s_bp[64+t] + s_bp[128+t] + s_bp[192+t] + s_b[4096+t];
      __syncthreads();
      cur ^= 1;
    } else {
      float* D = pt + (size_t)(c*16 + j)*4160;
      #pragma unroll
      for (int d = 0; d < 4; ++d)
        *(float4*)&D[(4*ti + d)*64 + 4*tj] =
            make_float4(acc[d][0], acc[d][1], acc[d][2], acc[d][3]);
      if (t < 64)
        D[4096 + t] = s_bp[t] + s_bp[64+t] + s_bp[128+t] + s_bp[192+t] + s_b[4096+t];
    }
  }
}

// ---------------------------------------------------------------------------
// D2: fold16_kernel (verbatim R13, passed). 32 blocks x 256 thr (4 waves).
// Block (c,q): column q of chain c; wave w owns k-slice [16w,16w+16);
// v via readlane SGPRs; chunks staged 2-deep into 3 LDS buffers via
// global_load_lds, counted vmcnt(10).
// ws: [0..512) node W_eff 32x16, [512..640) edge 8x16.
// ---------------------------------------------------------------------------
__global__ __launch_bounds__(256, 1) void fold16_kernel(
    const float* __restrict__ nWin, const float* __restrict__ nbin,
    const float* __restrict__ nWout, const float* __restrict__ nbout,
    const float* __restrict__ eWin, const float* __restrict__ ebin,
    const float* __restrict__ eWout, const float* __restrict__ ebout,
    const float* __restrict__ pt, float* __restrict__ ws)
{
  const int tid  = threadIdx.x;
  const int lane = tid & 63;
  const int wv   = __builtin_amdgcn_readfirstlane(tid >> 6);  // 0..3
  const int c = blockIdx.x >> 4;         // 0 node, 1 edge
  const int q = blockIdx.x & 15;         // output column
  const float* Win  = c ? eWin  : nWin;
  const float* bin  = c ? ebin  : nbin;
  const float* Wout = c ? eWout : nWout;
  const float* bout = c ? ebout : nbout;
  const float* PT = pt + (size_t)c*16*4160;
  const int din = c ? 7 : 31;
  float* weff = ws + (c ? 512 : 0);

  __shared__ float lds_f[13312];   // 3*4352 buffers + 256 partials = 53 KB

  const int r4 = lane >> 4, c16 = lane & 15;
  const int oE = r4*64 + ((c16 ^ r4) << 2);        // GLD4 slot parity even
  const int oO = r4*64 + ((c16 ^ (4 | r4)) << 2);  // GLD4 slot parity odd
  const int swz = lane & 7;
  const int aw0 = lane*256 + (((4*wv + 0) ^ swz) << 4);
  const int aw1 = lane*256 + (((4*wv + 1) ^ swz) << 4);
  const int aw2 = lane*256 + (((4*wv + 2) ^ swz) << 4);
  const int aw3 = lane*256 + (((4*wv + 3) ^ swz) << 4);
  const int ab  = 16384 + wv*256 + lane*4;          // bias copy (per-wave)
  const int apw = 52224 + lane*16 + wv*4;           // partial write
  const int apr = 52224 + lane*16;                  // partial read (b128)

  float vlane = Wout[lane*16 + q];                  // V_16 column = Wout[:,q]
  float bpart = 0.f;
  const int kbase = 16*wv;
  float s[16];
  #pragma unroll
  for (int j = 0; j < 16; ++j)
    s[j] = __uint_as_float(__builtin_amdgcn_readlane(__float_as_uint(vlane), kbase + j));

#define STAGE(BF, L) do {                                                 \
    const float* gW_ = PT + (size_t)(L)*4160 + wv*1024;                   \
    float* lW_ = lds_f + (BF)*4352 + wv*1024;                             \
    GLD4(gW_ +   0 + oE, lW_ +   0);                                      \
    GLD4(gW_ + 256 + oO, lW_ + 256);                                      \
    GLD4(gW_ + 512 + oE, lW_ + 512);                                      \
    GLD4(gW_ + 768 + oO, lW_ + 768);                                      \
    GLD1(PT + (size_t)(L)*4160 + 4096 + lane,                             \
         lds_f + (BF)*4352 + 4096 + wv*64);                               \
  } while (0)

#define CSTEP(OFS, VMC, STAGESTMT) do {                                   \
    STAGESTMT;                                                            \
    asm volatile("s_waitcnt vmcnt(" #VMC ") lgkmcnt(0)" ::: "memory");    \
    __builtin_amdgcn_s_barrier();        /* this step's buffer ready */   \
    f4 f0_, f1_, f2_, f3_; float bb_;                                     \
    asm volatile("ds_read_b128 %0, %5 offset:" #OFS "\n\t"                \
                 "ds_read_b128 %1, %6 offset:" #OFS "\n\t"                \
                 "ds_read_b128 %2, %7 offset:" #OFS "\n\t"                \
                 "ds_read_b128 %3, %8 offset:" #OFS "\n\t"                \
                 "ds_read_b32  %4, %9 offset:" #OFS "\n\t"                \
                 "s_waitcnt lgkmcnt(0)"                                   \
                 : "=&v"(f0_), "=&v"(f1_), "=&v"(f2_), "=&v"(f3_), "=&v"(bb_) \
                 : "v"(aw0), "v"(aw1), "v"(aw2), "v"(aw3), "v"(ab)        \
                 : "memory");                                             \
    __builtin_amdgcn_sched_barrier(0);                                    \
    bpart = __builtin_fmaf(bb_, vlane, bpart);                            \
    float a0_ = __builtin_fmaf(f0_.y, s[1],  f0_.x * s[0]);               \
    a0_ = __builtin_fmaf(f0_.z, s[2],  a0_);                              \
    a0_ = __builtin_fmaf(f0_.w, s[3],  a0_);                              \
    float a1_ = __builtin_fmaf(f1_.y, s[5],  f1_.x * s[4]);               \
    a1_ = __builtin_fmaf(f1_.z, s[6],  a1_);                              \
    a1_ = __builtin_fmaf(f1_.w, s[7],  a1_);                              \
    float a2_ = __builtin_fmaf(f2_.y, s[9],  f2_.x * s[8]);               \
    a2_ = __builtin_fmaf(f2_.z, s[10], a2_);                              \
    a2_ = __builtin_fmaf(f2_.w, s[11], a2_);                              \
    float a3_ = __builtin_fmaf(f3_.y, s[13], f3_.x * s[12]);              \
    a3_ = __builtin_fmaf(f3_.z, s[14], a3_);                              \
    a3_ = __builtin_fmaf(f3_.w, s[15], a3_);                              \
    float acc_ = (a0_ + a1_) + (a2_ + a3_);                               \
    asm volatile("ds_write_b32 %0, %1\n\t"                                \
                 "s_waitcnt lgkmcnt(0)"                                   \
                 :: "v"(apw), "v"(acc_) : "memory");                      \
    __builtin_amdgcn_s_barrier();        /* partials visible */           \
    f4 p4_;                                                               \
    asm volatile("ds_read_b128 %0, %1\n\t"                                \
                 "s_waitcnt lgkmcnt(0)"                                   \
                 : "=&v"(p4_) : "v"(apr) : "memory");                     \
    __builtin_amdgcn_sched_barrier(0);                                    \
    vlane = (p4_.x + p4_.y) + (p4_.z + p4_.w);                            \
    _Pragma("unroll")                                                     \
    for (int jj = 0; jj < 16; ++jj)                                       \
      s[jj] = __uint_as_float(__builtin_amdgcn_readlane(                  \
                  __float_as_uint(vlane), kbase + jj));                   \
  } while (0)

  // prologue: prime buffers 0 (chunk 15) and 1 (chunk 14) -> 10 outstanding
  STAGE(0, 15);
  STAGE(1, 14);

  int L = 15;
  #pragma unroll 1
  for (int ii = 0; ii < 4; ++ii) {       // chunks 15..4
    CSTEP(0,     10, STAGE(2, L-2));
    CSTEP(17408, 10, STAGE(0, L-3));
    CSTEP(34816, 10, STAGE(1, L-4));
    L -= 3;
  }
  // tail: chunks 3,2,1,0
  CSTEP(0,     10, STAGE(2, 1));
  CSTEP(17408, 10, STAGE(0, 0));
  CSTEP(34816, 5,  (void)0);
  CSTEP(0,     0,  (void)0);
#undef CSTEP
#undef STAGE
  // vlane == V_0[lane]; bpart = lane's share of beta (identical in all waves)

  if (wv != 0) return;                   // no barriers below

  float red = __builtin_fmaf(bin[lane], vlane, bpart);
  #pragma unroll
  for (int off = 32; off > 0; off >>= 1) red += __shfl_xor(red, off, 64);

  float* sv = lds_f;                     // buffers dead; share v0 wave-locally
  sv[lane] = vlane;
  __builtin_amdgcn_sched_barrier(0);

  if (lane == din) {
    weff[din*16 + q] = red + bout[q];
  } else if (lane < din) {
    float a0 = 0.f, a1 = 0.f, a2 = 0.f, a3 = 0.f;
    const float* wr = Win + (size_t)lane*64;
    #pragma unroll
    for (int kb = 0; kb < 16; ++kb) {
      f4 vv = *(const f4*)&sv[kb*4];
      f4 wv4 = *(const f4*)&wr[kb*4];
      a0 = __builtin_fmaf(wv4.x, vv.x, a0);
      a1 = __builtin_fmaf(wv4.y, vv.y, a1);
      a2 = __builtin_fmaf(wv4.z, vv.z, a2);
      a3 = __builtin_fmaf(wv4.w, vv.w, a3);
    }
    weff[lane*16 + q] = (a0 + a1) + (a2 + a3);
  }
}

// ---------------------------------------------------------------------------
// D3: apply (verbatim R3..R13, ~2.3 µs, near HBM floor)
// ---------------------------------------------------------------------------
template<int NF>
static __device__ __forceinline__ void mlp_apply_store(const float* x, const float* sW,
                                                       float* po)
{
  float a[16];
  #pragma unroll
  for (int q = 0; q < 16; ++q) a[q] = sW[NF*16 + q];   // bias row
  #pragma unroll
  for (int j = 0; j < NF; ++j) {
    const float xv = x[j];
    #pragma unroll
    for (int q = 0; q < 16; ++q) a[q] += xv * sW[j*16 + q];
  }
  float4* d = (float4*)po;
  d[0] = make_float4(a[0],  a[1],  a[2],  a[3]);
  d[1] = make_float4(a[4],  a[5],  a[6],  a[7]);
  d[2] = make_float4(a[8],  a[9],  a[10], a[11]);
  d[3] = make_float4(a[12], a[13], a[14], a[15]);
}

__global__ __launch_bounds__(256) void apply_kernel(
    const float* __restrict__ nodes, const float* __restrict__ globals_,
    const float* __restrict__ edges, const int* __restrict__ senders,
    const int* __restrict__ receivers, const float* __restrict__ ws,
    float* __restrict__ out)
{
  __shared__ float sW[32*16];
  const bool is_node = (blockIdx.x < NODE_BLOCKS);
  {
    const float* src = is_node ? ws : ws + 512;
    const int n = is_node ? 32*16 : 8*16;
    for (int j = threadIdx.x; j < n; j += 256) sW[j] = src[j];
  }
  __syncthreads();

  if (is_node) {
    const int rn = blockIdx.x*256 + threadIdx.x;
    if (rn >= NODE_ROWS) return;
    float x[31];
    const float* p = nodes + (size_t)rn*30;
    #pragma unroll
    for (int j = 0; j < 15; ++j) {
      float2 u = *(const float2*)(p + j*2);
      x[2*j]     = u.x;
      x[2*j + 1] = u.y;
    }
    const int b = (rn >= NN) ? 1 : 0;
    x[30] = globals_[b];
    mlp_apply_store<31>(x, sW, out + (size_t)rn*16);
  } else {
    const int re = (blockIdx.x - NODE_BLOCKS)*256 + threadIdx.x;  // < 160000 exact
    const int b = (re >= EE_) ? 1 : 0;
    float x[7];
    const float* ep = edges + (size_t)re*3;
    x[0] = ep[0]; x[1] = ep[1]; x[2] = ep[2];
    const int si = senders[re], ri = receivers[re];
    const float* ps = nodes + ((size_t)(b*NN + si))*30;
    const float* pr = nodes + ((size_t)(b*NN + ri))*30;
    const float dx = ps[0] - pr[0];
    const float dy = ps[1] - pr[1];
    const float dz = ps[2] - pr[2];
    x[3] = dx; x[4] = dy; x[5] = dz;
    x[6] = sqrtf(dx*dx + dy*dy + dz*dz);
    mlp_apply_store<7>(x, sW, out + (size_t)(NODE_ROWS + re)*16);
  }
}

extern "C" void kernel_launch(void* const* d_in, const int* in_sizes, int n_in,
                              void* d_out, int out_size, void* d_ws, size_t ws_size,
                              hipStream_t stream)
{
  const float* nodes    = (const float*)d_in[0];
  const float* globals_ = (const float*)d_in[1];
  const float* edges    = (const float*)d_in[2];
  const int* senders   = (const int*)d_in[3];
  const int* receivers = (const int*)d_in[4];
  const float* nWin  = (const float*)d_in[5];
  const float* nbin  = (const float*)d_in[6];
  const float* nWhid = (const float*)d_in[7];
  const float* nbhid = (const float*)d_in[8];
  const float* nWout = (const float*)d_in[9];
  const float* nbout = (const float*)d_in[10];
  const float* eWin  = (const float*)d_in[11];
  const float* ebin  = (const float*)d_in[12];
  const float* eWhid = (const float*)d_in[13];
  const float* ebhid = (const float*)d_in[14];
  const float* eWout = (const float*)d_in[15];
  const float* ebout = (const float*)d_in[16];
  float* ws  = (float*)d_ws;
  float* out = (float*)d_out;
  float* pt  = ws + 1024;               // 32 slots x 4160 f

  chunk_kernel<<<32, 256, 0, stream>>>(nWhid, nbhid, eWhid, ebhid, pt);

  fold16_kernel<<<32, 256, 0, stream>>>(
      nWin, nbin, nWout, nbout, eWin, ebin, eWout, ebout, pt, ws);

  apply_kernel<<<NODE_BLOCKS + EDGE_BLOCKS, 256, 0, stream>>>(
      nodes, globals_, edges, senders, receivers, ws, out);
}